// Round 9
// baseline (196.341 us; speedup 1.0000x reference)
//
#include <hip/hip_runtime.h>

// ---------------------------------------------------------------------------
// MHA forward, B=8 S=1024 D=768 H=12 hd=64, fp32 in/out, bf16 MFMA compute.
// cvt3 -> QKV GEMM (8-wave 128x128, BK=32, 2-stage LDS dbuf, unroll-2 K-loop)
// -> flash attn (Q-tile 64, frag-linear conflict-free LDS layouts, KV dbuf,
//    XCD-local grid, no-max softmax) -> proj GEMM.
// Reference applies NO 1/sqrt(hd) scale.
// ---------------------------------------------------------------------------

typedef short bf16x8 __attribute__((ext_vector_type(8)));
typedef float f32x4  __attribute__((ext_vector_type(4)));

#define MFMA16(a, b, c) __builtin_amdgcn_mfma_f32_16x16x32_bf16((a), (b), (c), 0, 0, 0)

__device__ __forceinline__ unsigned short f2bf(float f) {
    union { float f; unsigned int u; } v; v.f = f;
    unsigned int u = v.u;
    return (unsigned short)((u + 0x7fffu + ((u >> 16) & 1u)) >> 16);  // RTNE
}

__device__ __forceinline__ unsigned int cvt2(float x, float y) {
#if __has_builtin(__builtin_amdgcn_cvt_pk_bf16_f32)
    auto v = __builtin_amdgcn_cvt_pk_bf16_f32(x, y);
    unsigned int b; __builtin_memcpy(&b, &v, 4); return b;
#else
    return (unsigned int)f2bf(x) | ((unsigned int)f2bf(y) << 16);
#endif
}

__device__ __forceinline__ void gl2lds16(const unsigned short* g, unsigned short* l) {
    __builtin_amdgcn_global_load_lds(
        (const unsigned int __attribute__((address_space(1)))*)g,
        (unsigned int __attribute__((address_space(3)))*)l,
        16, 0, 0);
}

// ---------------------------------------------------------------------------
// fused fp32->bf16 convert for x, w_qkv, w_proj (grid exactly 8448*256 float4s)
__global__ void cvt3_kernel(const float* __restrict__ x,
                            const float* __restrict__ wq,
                            const float* __restrict__ wp,
                            unsigned short* __restrict__ xb,
                            unsigned short* __restrict__ wqb,
                            unsigned short* __restrict__ wpb) {
    int i = blockIdx.x * 256 + threadIdx.x;
    const float* s; unsigned short* d; int off;
    if (i < 1572864)      { s = x;  d = xb;  off = i; }
    else if (i < 2015232) { s = wq; d = wqb; off = i - 1572864; }
    else                  { s = wp; d = wpb; off = i - 2015232; }
    float4 v = ((const float4*)s)[off];
    ushort4 o;
    o.x = f2bf(v.x); o.y = f2bf(v.y); o.z = f2bf(v.z); o.w = f2bf(v.w);
    ((ushort4*)d)[off] = o;
}

// ---------------------------------------------------------------------------
// GEMM1: C[8192,2304] = Xbf[8192,768] * Wqkv[2304,768]^T + bias.
// 512 thr = 8 waves, 128x128 tile, BK=32, double-buffered LDS (unroll-2).
// blockIdx.y 0-5 -> Q [B,S,768] (scaled log2e), 6-11 -> K, 12-17 -> V^T.
__global__ __launch_bounds__(512, 4) void gemm_qkv(
    const unsigned short* __restrict__ A,   // [8192][768]
    const unsigned short* __restrict__ Bm,  // [2304][768]
    const float* __restrict__ bias,         // [2304]
    unsigned short* __restrict__ Qo,        // [B,S,768]
    unsigned short* __restrict__ Ko,        // [B,S,768]
    unsigned short* __restrict__ Vto) {     // [B,H,64,S]
    const int K = 768;
    __shared__ __align__(16) unsigned short smem[16384];  // A0|A1|B0|B1; V-epi reuses
    unsigned short* const As0 = smem;
    unsigned short* const As1 = smem + 4096;
    unsigned short* const Bs0 = smem + 8192;
    unsigned short* const Bs1 = smem + 12288;
    const int tid = threadIdx.x;
    const int wave = tid >> 6, lane = tid & 63;
    const int quad = lane >> 4, l16 = lane & 15;
    const int wm = (wave >> 1) * 32, wn = (wave & 1) * 64;
    const int tileM = blockIdx.x * 128, tileN = blockIdx.y * 128;

    f32x4 zero4 = {0.f, 0.f, 0.f, 0.f};
    f32x4 acc[2][4];
#pragma unroll
    for (int i = 0; i < 2; ++i)
#pragma unroll
        for (int j = 0; j < 4; ++j) acc[i][j] = zero4;

    const int sr = tid >> 2, sc = tid & 3;
    const unsigned short* Ag = A + (size_t)(tileM + sr) * K + sc * 8;
    const unsigned short* Bg = Bm + (size_t)(tileN + sr) * K + sc * 8;
    const int sdst = wave << 9;  // shorts

    auto compute = [&](const unsigned short* Ar, const unsigned short* Br) {
        bf16x8 af[2], bfr[4];
#pragma unroll
        for (int t = 0; t < 2; ++t)
            af[t] = *(const bf16x8*)(Ar + (wm + t * 16 + l16) * 32 + quad * 8);
#pragma unroll
        for (int t = 0; t < 4; ++t)
            bfr[t] = *(const bf16x8*)(Br + (wn + t * 16 + l16) * 32 + quad * 8);
#pragma unroll
        for (int tm = 0; tm < 2; ++tm)
#pragma unroll
            for (int tn = 0; tn < 4; ++tn)
                acc[tm][tn] = MFMA16(af[tm], bfr[tn], acc[tm][tn]);
    };

    gl2lds16(Ag, As0 + sdst);
    gl2lds16(Bg, Bs0 + sdst);
    for (int it = 0; it < 24; it += 2) {
        __syncthreads();
        {
            int k1 = (it + 1) << 5;
            gl2lds16(Ag + k1, As1 + sdst);
            gl2lds16(Bg + k1, Bs1 + sdst);
        }
        compute(As0, Bs0);
        __syncthreads();
        if (it + 2 < 24) {
            int k2 = (it + 2) << 5;
            gl2lds16(Ag + k2, As0 + sdst);
            gl2lds16(Bg + k2, Bs0 + sdst);
        }
        compute(As1, Bs1);
    }

    const int t = blockIdx.y / 6;  // 0=Q 1=K 2=V (tile never straddles)
    if (t < 2) {
        const float scale = (t == 0) ? 1.44269504f : 1.0f;  // fold log2e into Q
        unsigned short* dst = (t == 0) ? Qo : Ko;
        const int nb = tileN - t * 768 + wn;
#pragma unroll
        for (int tm = 0; tm < 2; ++tm) {
#pragma unroll
            for (int tn = 0; tn < 4; ++tn) {
                int nl = nb + tn * 16 + l16;
                float bv = bias[tileN + wn + tn * 16 + l16];
#pragma unroll
                for (int r = 0; r < 4; ++r) {
                    int m = tileM + wm + tm * 16 + quad * 4 + r;
                    dst[(size_t)m * 768 + nl] = f2bf((acc[tm][tn][r] + bv) * scale);
                }
            }
        }
    } else {
        // V: stage [64 d][128 s] half in LDS (stride 136 shorts), store coalesced
        const int b = tileM >> 10, srow = tileM & 1023;
#pragma unroll
        for (int h2 = 0; h2 < 2; ++h2) {
            __syncthreads();
            if ((wave & 1) == h2) {
#pragma unroll
                for (int tn = 0; tn < 4; ++tn) {
                    int dl = tn * 16 + l16;
                    float bv = bias[tileN + h2 * 64 + dl];
#pragma unroll
                    for (int tm = 0; tm < 2; ++tm) {
                        int mb = wm + tm * 16 + quad * 4;
                        uint2 pk;
                        pk.x = cvt2(acc[tm][tn][0] + bv, acc[tm][tn][1] + bv);
                        pk.y = cvt2(acc[tm][tn][2] + bv, acc[tm][tn][3] + bv);
                        *(uint2*)(smem + dl * 136 + mb) = pk;
                    }
                }
            }
            __syncthreads();
#pragma unroll
            for (int pass = 0; pass < 2; ++pass) {
                int dl = pass * 32 + (tid >> 4), soff = (tid & 15) * 8;
                bf16x8 row = *(const bf16x8*)(smem + dl * 136 + soff);
                int rem = tileN + h2 * 64 + dl - 1536;
                int h = rem >> 6, d = rem & 63;
                *(bf16x8*)(Vto + (((size_t)b * 12 + h) * 64 + d) * 1024 + srow + soff) = row;
            }
        }
    }
}

// ---------------------------------------------------------------------------
// Flash attention, Q-tile 64, frag-linear LDS (conflict-free frag reads).
// Every tile is stored so a frag's 64 lanes read consecutive 16B granules.
// LDS 40KB: P/Q strips 8KB | K dbuf 16KB | V dbuf 16KB -> 4 blocks/CU.
// Grid (96,16): bh fastest -> XCD = bh%8, KV L2-resident per XCD.
__global__ __launch_bounds__(256, 4) void attn_kernel(
    const unsigned short* __restrict__ Q,
    const unsigned short* __restrict__ Kg,
    const unsigned short* __restrict__ Vt,
    unsigned short* __restrict__ O) {       // [B,S,768] bf16
    __shared__ __align__(16) unsigned short smem[20480];  // 40 KB

    const int tid = threadIdx.x;
    const int wave = tid >> 6, lane = tid & 63;
    const int quad = lane >> 4, l16 = lane & 15;
    const int bh = blockIdx.x;               // 0..95  (XCD = bh % 8)
    const int qt = blockIdx.y;               // 0..15
    const int b = bh / 12, h = bh - b * 12;

    const unsigned short* Qb = Q  + ((size_t)b * 1024 + qt * 64) * 768 + h * 64;
    const unsigned short* Kb = Kg + (size_t)b * 1024 * 768 + h * 64;
    const unsigned short* Vb = Vt + (size_t)bh * 64 * 1024;

    // frag-linear staging: wave handles combos c0,c1; lane granule=(quad,l16)
    // K granule (ks=c>>2, tk=c&3): K[kv=tk*16+l16][d=ks*32+quad*8 ..+8]
    // V granule (ks2=c>>2, tv=c&3): V^T[d=tv*16+l16][kv=kv0+ks2*32+quad*8 ..+8]
    const int c0 = wave * 2, c1 = c0 + 1;
    const unsigned short* gk0 = Kb + (size_t)((c0 & 3) * 16 + l16) * 768 + (c0 >> 2) * 32 + quad * 8;
    const unsigned short* gk1 = Kb + (size_t)((c1 & 3) * 16 + l16) * 768 + (c1 >> 2) * 32 + quad * 8;
    const unsigned short* gv0 = Vb + (size_t)((c0 & 3) * 16 + l16) * 1024 + (c0 >> 2) * 32 + quad * 8;
    const unsigned short* gv1 = Vb + (size_t)((c1 & 3) * 16 + l16) * 1024 + (c1 >> 2) * 32 + quad * 8;

    auto stageKV = [&](int kv0, int buf) {
        unsigned short* Kd = smem + 4096 + buf * 4096;
        unsigned short* Vd = smem + 12288 + buf * 4096;
        gl2lds16(gk0 + (size_t)kv0 * 768, Kd + c0 * 512);
        gl2lds16(gk1 + (size_t)kv0 * 768, Kd + c1 * 512);
        gl2lds16(gv0 + kv0, Vd + c0 * 512);
        gl2lds16(gv1 + kv0, Vd + c1 * 512);
    };

    // Q: wave-local staging into own strip [wave*1024, +1024) shorts
    gl2lds16(Qb + (size_t)(wave * 16 + l16) * 768 + quad * 8,      smem + c0 * 512);
    gl2lds16(Qb + (size_t)(wave * 16 + l16) * 768 + 32 + quad * 8, smem + c1 * 512);
    stageKV(0, 0);
    __syncthreads();
    bf16x8 qf[2];  // B-operand: Q[q=l16][d=ks*32+quad*8 ..+8]
    qf[0] = *(const bf16x8*)(smem + c0 * 512 + lane * 8);
    qf[1] = *(const bf16x8*)(smem + c1 * 512 + lane * 8);

    unsigned short* Pw = smem + wave * 1024;  // wave's P strip (A-frag-linear)
    f32x4 zero4 = {0.f, 0.f, 0.f, 0.f};
    f32x4 oacc[4];
    float rsum = 0.f;
#pragma unroll
    for (int tv = 0; tv < 4; ++tv) oacc[tv] = zero4;

    for (int it = 0; it < 16; ++it) {
        if (it + 1 < 16) stageKV((it + 1) << 6, (it + 1) & 1);
        const unsigned short* Kr = smem + 4096 + (it & 1) * 4096;
        const unsigned short* Vr = smem + 12288 + (it & 1) * 4096;

        // S^T: lane holds S^T[kv=tk*16+quad*4+r][q=l16]
        f32x4 st[4];
#pragma unroll
        for (int tk = 0; tk < 4; ++tk) st[tk] = zero4;
#pragma unroll
        for (int ks = 0; ks < 2; ++ks) {
            bf16x8 kf[4];
#pragma unroll
            for (int tk = 0; tk < 4; ++tk)
                kf[tk] = *(const bf16x8*)(Kr + (ks * 4 + tk) * 512 + lane * 8);
#pragma unroll
            for (int tk = 0; tk < 4; ++tk)
                st[tk] = MFMA16(kf[tk], qf[ks], st[tk]);
        }

        // P = exp2(S^T): write into frag-linear P strip
        // (q=l16, kv=tk*16+quad*4+r) -> granule g=tk*2+(quad>>1), sub=(quad&1)*4
#pragma unroll
        for (int tk = 0; tk < 4; ++tk) {
            float e0 = __builtin_amdgcn_exp2f(st[tk][0]);
            float e1 = __builtin_amdgcn_exp2f(st[tk][1]);
            float e2 = __builtin_amdgcn_exp2f(st[tk][2]);
            float e3 = __builtin_amdgcn_exp2f(st[tk][3]);
            rsum += (e0 + e1) + (e2 + e3);
            uint2 pk;
            pk.x = cvt2(e0, e1);
            pk.y = cvt2(e2, e3);
            *(uint2*)(Pw + (tk * 2 + (quad >> 1)) * 128 + l16 * 8 + (quad & 1) * 4) = pk;
        }

        // O += P*V: A-frag ap lane-linear; bv frag-linear (conflict-free)
#pragma unroll
        for (int ks2 = 0; ks2 < 2; ++ks2) {
            bf16x8 ap = *(const bf16x8*)(Pw + ks2 * 512 + lane * 8);
            bf16x8 bv[4];
#pragma unroll
            for (int tv = 0; tv < 4; ++tv)
                bv[tv] = *(const bf16x8*)(Vr + (ks2 * 4 + tv) * 512 + lane * 8);
#pragma unroll
            for (int tv = 0; tv < 4; ++tv)
                oacc[tv] = MFMA16(ap, bv[tv], oacc[tv]);
        }
        __syncthreads();  // next KV tile ready; this buf's readers done
    }

    // row sums: reduce across quads (all lanes get sum for q=l16), then
    // redistribute so lane gets sum for its output rows q=quad*4+r
    rsum += __shfl_xor(rsum, 16, 64);
    rsum += __shfl_xor(rsum, 32, 64);
    float inv[4];
#pragma unroll
    for (int r = 0; r < 4; ++r)
        inv[r] = 1.0f / __shfl(rsum, quad * 4 + r, 64);

    // epilogue: O[b, s=qt*64+wave*16+quad*4+r, h*64 + tv*16 + l16]
#pragma unroll
    for (int tv = 0; tv < 4; ++tv)
#pragma unroll
        for (int r = 0; r < 4; ++r) {
            int srow = qt * 64 + wave * 16 + quad * 4 + r;
            int col = h * 64 + tv * 16 + l16;
            O[((size_t)b * 1024 + srow) * 768 + col] = f2bf(oacc[tv][r] * inv[r]);
        }
}

// ---------------------------------------------------------------------------
// GEMM3: out[8192,768] = Obf[8192,768] * Wproj[768,768]^T + bias, fp32 out.
__global__ __launch_bounds__(512, 4) void gemm_proj(
    const unsigned short* __restrict__ A,
    const unsigned short* __restrict__ Bm,
    const float* __restrict__ bias,
    float* __restrict__ out) {
    const int K = 768;
    __shared__ __align__(16) unsigned short smem[16384];
    unsigned short* const As0 = smem;
    unsigned short* const As1 = smem + 4096;
    unsigned short* const Bs0 = smem + 8192;
    unsigned short* const Bs1 = smem + 12288;
    const int tid = threadIdx.x;
    const int wave = tid >> 6, lane = tid & 63;
    const int quad = lane >> 4, l16 = lane & 15;
    const int wm = (wave >> 1) * 32, wn = (wave & 1) * 64;
    const int tileM = blockIdx.x * 128, tileN = blockIdx.y * 128;

    f32x4 zero4 = {0.f, 0.f, 0.f, 0.f};
    f32x4 acc[2][4];
#pragma unroll
    for (int i = 0; i < 2; ++i)
#pragma unroll
        for (int j = 0; j < 4; ++j) acc[i][j] = zero4;

    const int sr = tid >> 2, sc = tid & 3;
    const unsigned short* Ag = A + (size_t)(tileM + sr) * K + sc * 8;
    const unsigned short* Bg = Bm + (size_t)(tileN + sr) * K + sc * 8;
    const int sdst = wave << 9;

    auto compute = [&](const unsigned short* Ar, const unsigned short* Br) {
        bf16x8 af[2], bfr[4];
#pragma unroll
        for (int t = 0; t < 2; ++t)
            af[t] = *(const bf16x8*)(Ar + (wm + t * 16 + l16) * 32 + quad * 8);
#pragma unroll
        for (int t = 0; t < 4; ++t)
            bfr[t] = *(const bf16x8*)(Br + (wn + t * 16 + l16) * 32 + quad * 8);
#pragma unroll
        for (int tm = 0; tm < 2; ++tm)
#pragma unroll
            for (int tn = 0; tn < 4; ++tn)
                acc[tm][tn] = MFMA16(af[tm], bfr[tn], acc[tm][tn]);
    };

    gl2lds16(Ag, As0 + sdst);
    gl2lds16(Bg, Bs0 + sdst);
    for (int it = 0; it < 24; it += 2) {
        __syncthreads();
        {
            int k1 = (it + 1) << 5;
            gl2lds16(Ag + k1, As1 + sdst);
            gl2lds16(Bg + k1, Bs1 + sdst);
        }
        compute(As0, Bs0);
        __syncthreads();
        if (it + 2 < 24) {
            int k2 = (it + 2) << 5;
            gl2lds16(Ag + k2, As0 + sdst);
            gl2lds16(Bg + k2, Bs0 + sdst);
        }
        compute(As1, Bs1);
    }

#pragma unroll
    for (int tm = 0; tm < 2; ++tm) {
#pragma unroll
        for (int tn = 0; tn < 4; ++tn) {
            int n = tileN + wn + tn * 16 + l16;
            float bv = bias[n];
#pragma unroll
            for (int r = 0; r < 4; ++r) {
                int m = tileM + wm + tm * 16 + quad * 4 + r;
                out[(size_t)m * 768 + n] = acc[tm][tn][r] + bv;
            }
        }
    }
}

// ---------------------------------------------------------------------------
extern "C" void kernel_launch(void* const* d_in, const int* in_sizes, int n_in,
                              void* d_out, int out_size, void* d_ws, size_t ws_size,
                              hipStream_t stream) {
    (void)in_sizes; (void)n_in; (void)out_size; (void)ws_size;
    const float* x      = (const float*)d_in[0];
    const float* w_qkv  = (const float*)d_in[1];
    const float* b_qkv  = (const float*)d_in[2];
    const float* w_proj = (const float*)d_in[3];
    const float* b_proj = (const float*)d_in[4];
    float* out = (float*)d_out;

    char* ws = (char*)d_ws;
    unsigned short* xb     = (unsigned short*)(ws + 0);         // bf16 X, then attn O
    unsigned short* wqkvb  = (unsigned short*)(ws + 12582912);
    unsigned short* wprojb = (unsigned short*)(ws + 16121856);
    unsigned short* Qw     = (unsigned short*)(ws + 17301504);  // [B,S,768]
    unsigned short* Kw     = (unsigned short*)(ws + 29884416);  // [B,S,768]
    unsigned short* Vtw    = (unsigned short*)(ws + 42467328);  // [B,H,64,S]

    cvt3_kernel<<<8448, 256, 0, stream>>>(x, w_qkv, w_proj, xb, wqkvb, wprojb);
    gemm_qkv<<<dim3(64, 18), 512, 0, stream>>>(xb, wqkvb, b_qkv, Qw, Kw, Vtw);
    // (96, 16): bh fastest -> XCD = bh % 8; q-tiles of one (b,h) share an XCD/L2
    attn_kernel<<<dim3(96, 16), 256, 0, stream>>>(Qw, Kw, Vtw, xb);
    gemm_proj<<<dim3(64, 6), 512, 0, stream>>>(xb, wprojb, b_proj, out);
}